// Round 4
// baseline (110.117 us; speedup 1.0000x reference)
//
#include <hip/hip_runtime.h>
#include <math.h>

namespace {
constexpr int K = 15;
constexpr int FD = 128;
constexpr int FS = 160;
constexpr int OV = 40;
constexpr int NFRAMES = 500;
constexpr int NSAMP = NFRAMES * FS;   // 80000
constexpr float C_CONST = 0.11512925464970229f;
constexpr float LOG_GAIN_LIMIT = 10.0f * C_CONST;
constexpr float GAIN_A = 6.0f * C_CONST;
constexpr float PI_F = 3.14159265358979323846f;

// ---- K1 (params) ----
constexpr int K1FPB = 15;             // frames per block (15*17 = 255 <= 256)
constexpr int SFSTR = 132;            // padded feature row stride

// ---- K2 (synthesis) ----
constexpr int FPB = 10;               // frames per block (500 % 10 == 0)
constexpr int NFR = FPB + 1;          // + previous frame for overlap-add tail
constexpr int NW4 = 55;               // float4 window loads per frame
constexpr int WINA = 220;             // window row allocation (floats)
}

// =====================  K1: per-frame params  =====================
// params[g][0..14] = ggain*gain*inv_norm * kern[k];  params[g][15] = ggain
__global__ __launch_bounds__(256)
void params_kernel(const float* __restrict__ feat,   // (G, FD) flat
                   const float* __restrict__ ck_w,   // (K, FD)
                   const float* __restrict__ ck_b,   // (K)
                   const float* __restrict__ fg_w,   // (FD)
                   const float* __restrict__ fg_b,   // (1)
                   const float* __restrict__ gg_w,   // (FD)
                   const float* __restrict__ gg_b,   // (1)
                   float* __restrict__ params,       // (G, 16)
                   int G)
{
    const int tid = threadIdx.x;
    const int g0  = blockIdx.x * K1FPB;

    __shared__ __align__(16) float sfeat[K1FPB][SFSTR];
    __shared__ float sdots[K1FPB][17];

    // stage features (coalesced float4)
    for (int i = tid; i < K1FPB * (FD / 4); i += 256) {
        const int fi = i >> 5;          // /32
        const int e4 = i & 31;
        const int g  = g0 + fi;
        float4 v = make_float4(0.f, 0.f, 0.f, 0.f);
        if (g < G) v = ((const float4*)feat)[(size_t)g * (FD / 4) + e4];
        *(float4*)&sfeat[fi][e4 * 4] = v;
    }
    __syncthreads();

    // one thread per (frame, dot)
    if (tid < K1FPB * 17) {
        const int fi = tid / 17;
        const int j  = tid - fi * 17;
        const float* wrow = (j < K) ? (ck_w + (size_t)j * FD)
                                    : ((j == K) ? fg_w : gg_w);
        const float4* w4 = (const float4*)wrow;
        const float4* f4 = (const float4*)&sfeat[fi][0];
        float4 acc = make_float4(0.f, 0.f, 0.f, 0.f);
        #pragma unroll
        for (int i = 0; i < FD / 4; ++i) {
            const float4 a = f4[i];
            const float4 w = w4[i];
            acc.x += a.x * w.x; acc.y += a.y * w.y;
            acc.z += a.z * w.z; acc.w += a.w * w.w;
        }
        const float bias = (j < K) ? ck_b[j] : ((j == K) ? fg_b[0] : gg_b[0]);
        sdots[fi][j] = acc.x + acc.y + acc.z + acc.w + bias;
    }
    __syncthreads();

    // finalize: one thread per frame
    if (tid < K1FPB) {
        const int g = g0 + tid;
        if (g < G) {
            float kern[K];
            float n2 = 0.f;
            #pragma unroll
            for (int k = 0; k < K; ++k) {
                kern[k] = sdots[tid][k];
                n2 += kern[k] * kern[k];
            }
            const float inv   = 1.f / (1e-6f + sqrtf(n2));
            const float gain  = expf(-fmaxf(sdots[tid][K], 0.f) + LOG_GAIN_LIMIT);
            const float ggain = expf(GAIN_A * tanhf(sdots[tid][K + 1]));
            const float ks    = ggain * gain * inv;
            float p[16];
            #pragma unroll
            for (int k = 0; k < K; ++k) p[k] = ks * kern[k];
            p[15] = ggain;
            float4* dst = (float4*)(params + (size_t)g * 16);
            dst[0] = *(float4*)&p[0];
            dst[1] = *(float4*)&p[4];
            dst[2] = *(float4*)&p[8];
            dst[3] = *(float4*)&p[12];
        }
    }
}

// =====================  K2: synthesis  =====================
__global__ __launch_bounds__(256)
void synth_kernel(const float* __restrict__ x,      // (B, NSAMP)
                  const int*   __restrict__ lags,   // (B, NF)
                  const float* __restrict__ params, // (G, 16)
                  float* __restrict__ out)          // (B, NSAMP)
{
    const int tid = threadIdx.x;
    const int bid = blockIdx.x;
    const int b   = bid / (NFRAMES / FPB);
    const int blk = bid - b * (NFRAMES / FPB);
    const int f0  = blk * FPB;

    __shared__ __align__(16) float swin[NFR][WINA];  // swin[fr][l] = x[base_fr + l]
    __shared__ __align__(16) float sfk[NFR][16];
    __shared__ __align__(16) float swin2[OV + 8];

    const float* xb = x + (size_t)b * NSAMP;

    // stage windows
    for (int i = tid; i < NFR * NW4; i += 256) {
        const int fr = i / NW4;
        const int m  = i - fr * NW4;
        const int pf = f0 - 1 + fr;
        float4 v = make_float4(0.f, 0.f, 0.f, 0.f);
        if (pf >= 0) {
            const int base = pf * FS - lags[b * NFRAMES + pf] - 7;
            const int idx  = base + 4 * m;   // 4B-aligned float4 load is legal
            if (idx >= 0 && idx + 3 < NSAMP) {
                v = *(const float4*)(xb + idx);
            } else {
                if (idx     >= 0 && idx     < NSAMP) v.x = xb[idx];
                if (idx + 1 >= 0 && idx + 1 < NSAMP) v.y = xb[idx + 1];
                if (idx + 2 >= 0 && idx + 2 < NSAMP) v.z = xb[idx + 2];
                if (idx + 3 >= 0 && idx + 3 < NSAMP) v.w = xb[idx + 3];
            }
        }
        *(float4*)&swin[fr][4 * m] = v;
    }

    // stage params (NFR*4 = 44 float4 loads)
    if (tid < NFR * 4) {
        const int fr = tid >> 2;
        const int q  = tid & 3;
        const int pf = f0 - 1 + fr;
        float4 v = make_float4(0.f, 0.f, 0.f, 0.f);
        if (pf >= 0)
            v = ((const float4*)(params + ((size_t)b * NFRAMES + pf) * 16))[q];
        *(float4*)&sfk[fr][q * 4] = v;
    }

    if (tid >= 64 && tid < 64 + OV) {
        const int t = tid - 64;
        swin2[t] = 0.5f + 0.5f * cosf(((float)t + 0.5f) * (PI_F / OV));
    }
    __syncthreads();

    // conv + crossfade, 4 outputs per thread, all 16B ops
    const int obase = f0 * FS;
    for (int g = tid; g < FPB * (FS / 4); g += 256) {
        const int frl = g / (FS / 4);        // 0..FPB-1
        const int gi  = g - frl * (FS / 4);  // 0..39
        const int t   = gi * 4;
        const int fr  = frl + 1;

        const float4 k0 = *(const float4*)&sfk[fr][0];
        const float4 k1 = *(const float4*)&sfk[fr][4];
        const float4 k2 = *(const float4*)&sfk[fr][8];
        const float4 k3 = *(const float4*)&sfk[fr][12];
        const float kc[16] = {k0.x,k0.y,k0.z,k0.w, k1.x,k1.y,k1.z,k1.w,
                              k2.x,k2.y,k2.z,k2.w, k3.x,k3.y,k3.z,k3.w};

        float w[20];
        #pragma unroll
        for (int q = 0; q < 5; ++q)
            *(float4*)&w[4 * q] = *(const float4*)&swin[fr][t + 4 * q];

        const float4 pt = *(const float4*)(xb + obase + frl * FS + t);

        float4 res;
        {
            float c0 = 0.f, c1 = 0.f, c2 = 0.f, c3 = 0.f;
            #pragma unroll
            for (int k = 0; k < K; ++k) {
                const float kk = kc[k];
                c0 += w[k]     * kk;
                c1 += w[k + 1] * kk;
                c2 += w[k + 2] * kk;
                c3 += w[k + 3] * kk;
            }
            const float ps = kc[15];
            res.x = c0 + ps * pt.x; res.y = c1 + ps * pt.y;
            res.z = c2 + ps * pt.z; res.w = c3 + ps * pt.w;
        }

        if (gi < OV / 4) {   // head: crossfade with previous frame tail
            const float4 q0 = *(const float4*)&sfk[fr - 1][0];
            const float4 q1 = *(const float4*)&sfk[fr - 1][4];
            const float4 q2 = *(const float4*)&sfk[fr - 1][8];
            const float4 q3 = *(const float4*)&sfk[fr - 1][12];
            const float qc[16] = {q0.x,q0.y,q0.z,q0.w, q1.x,q1.y,q1.z,q1.w,
                                  q2.x,q2.y,q2.z,q2.w, q3.x,q3.y,q3.z,q3.w};
            float wv[20];
            #pragma unroll
            for (int q = 0; q < 5; ++q)
                *(float4*)&wv[4 * q] = *(const float4*)&swin[fr - 1][FS + t + 4 * q];

            float c0 = 0.f, c1 = 0.f, c2 = 0.f, c3 = 0.f;
            #pragma unroll
            for (int k = 0; k < K; ++k) {
                const float kk = qc[k];
                c0 += wv[k]     * kk;
                c1 += wv[k + 1] * kk;
                c2 += wv[k + 2] * kk;
                c3 += wv[k + 3] * kk;
            }
            const float ps = qc[15];
            const float4 tail = make_float4(c0 + ps * pt.x, c1 + ps * pt.y,
                                            c2 + ps * pt.z, c3 + ps * pt.w);
            const float4 w2 = *(const float4*)&swin2[t];
            res.x = res.x * (1.f - w2.x) + tail.x * w2.x;
            res.y = res.y * (1.f - w2.y) + tail.y * w2.y;
            res.z = res.z * (1.f - w2.z) + tail.z * w2.z;
            res.w = res.w * (1.f - w2.w) + tail.w * w2.w;
        }

        *(float4*)(out + (size_t)b * NSAMP + obase + frl * FS + t) = res;
    }
}

extern "C" void kernel_launch(void* const* d_in, const int* in_sizes, int n_in,
                              void* d_out, int out_size, void* d_ws, size_t ws_size,
                              hipStream_t stream) {
    const float* x    = (const float*)d_in[0];
    const float* feat = (const float*)d_in[1];
    const int*   lags = (const int*)d_in[2];
    const float* ck_w = (const float*)d_in[3];
    const float* ck_b = (const float*)d_in[4];
    const float* fg_w = (const float*)d_in[5];
    const float* fg_b = (const float*)d_in[6];
    const float* gg_w = (const float*)d_in[7];
    const float* gg_b = (const float*)d_in[8];
    float* out    = (float*)d_out;
    float* params = (float*)d_ws;      // (B*NFRAMES, 16) floats = 1 MB

    const int B = in_sizes[0] / NSAMP;
    const int G = B * NFRAMES;

    const int nblk1 = (G + K1FPB - 1) / K1FPB;
    params_kernel<<<dim3(nblk1), dim3(256), 0, stream>>>(
        feat, ck_w, ck_b, fg_w, fg_b, gg_w, gg_b, params, G);

    const int nblk2 = B * (NFRAMES / FPB);
    synth_kernel<<<dim3(nblk2), dim3(256), 0, stream>>>(
        x, lags, params, out);
}